// Round 15
// baseline (359.615 us; speedup 1.0000x reference)
//
#include <hip/hip_runtime.h>
#include <cstdint>
#include <cstddef>

// ---------------------------------------------------------------------------
// WindowGCN: 2-layer GCN + mean-pool + linear head.
// R15: gathers are at their compulsory-miss floor (FETCH = 8 XCD x table,
//      time ~ miss count at ~12G lines/s). Remaining lever: HIDE the GEMMs
//      under the gathers -- 3-chunk software pipeline, fused role-split
//      kernels (1 GEMM block per 16 agg blocks, launch_bounds(256,4),
//      GEMM role reads B from L2 to keep VGPR<=128). Everything else = R14.
// ---------------------------------------------------------------------------

typedef __attribute__((ext_vector_type(8))) short bf16x8;
typedef __attribute__((ext_vector_type(4))) float f32x4;

#define P1_CHUNK 4096
#define BCAP 8192

__device__ inline unsigned short f2bf(float f) {  // RNE fp32 -> bf16
    unsigned u = __float_as_uint(f);
    u = (u + 0x7FFFu + ((u >> 16) & 1u)) >> 16;
    return (unsigned short)u;
}
__device__ inline unsigned nib4(unsigned u) {
    return (u & 15u) | (((u >> 8) & 15u) << 4) | (((u >> 16) & 15u) << 8) |
           (((u >> 24) & 15u) << 12);
}
__device__ inline unsigned nibexp(unsigned h) {  // 4 nibbles -> 4 bytes
    unsigned t = (h | (h << 8)) & 0x00FF00FFu;
    return (t | (t << 4)) & 0x0F0F0F0Fu;
}
__device__ inline float ub(unsigned u, int q) { return (float)((u >> (8 * q)) & 255u); }

// ------- merged prep: bucket scatter | W transposes | graph hist | x->q4 ----
__global__ __launch_bounds__(256) void scatter_prep_kernel(
        const int* __restrict__ src, const int* __restrict__ dst,
        int* __restrict__ bucketCnt, unsigned* __restrict__ pairs, int E, int NB, int EB,
        const float* __restrict__ W1, unsigned short* __restrict__ WT1, int K1,
        const float* __restrict__ W2, unsigned short* __restrict__ WT2,
        const int* __restrict__ batch, int* __restrict__ cnt, int N, int HB,
        const float* __restrict__ x, unsigned char* __restrict__ Y0q,
        float* __restrict__ scaleRaw) {
    __shared__ int hist[512];
    __shared__ int base[512];
    int bid = blockIdx.x, t = threadIdx.x;
    if (bid < EB) {
        int e0 = bid * P1_CHUNK;
        int eend = min(e0 + P1_CHUNK, E);
        for (int i = t; i < NB; i += 256) hist[i] = 0;
        __syncthreads();
        for (int e = e0 + t; e < eend; e += 256) atomicAdd(&hist[dst[e] >> 8], 1);
        __syncthreads();
        for (int i = t; i < NB; i += 256) {
            int c = hist[i];
            base[i] = (c > 0) ? atomicAdd(&bucketCnt[i], c) : 0;
            hist[i] = 0;
        }
        __syncthreads();
        for (int e = e0 + t; e < eend; e += 256) {
            int d = dst[e], s = src[e];
            int b = d >> 8;
            int r = base[b] + atomicAdd(&hist[b], 1);
            if (r < BCAP)
                pairs[(size_t)b * BCAP + r] = (unsigned)s | ((unsigned)(d & 255) << 24);
        }
    } else if (bid < EB + K1) {
        int idx = (bid - EB) * 256 + t;
        int k = idx >> 8, n = idx & 255;
        WT1[n * K1 + k] = f2bf(W1[idx]);
    } else if (bid < EB + K1 + 256) {
        int idx = (bid - EB - K1) * 256 + t;
        int k = idx >> 8, n = idx & 255;
        WT2[n * 256 + k] = f2bf(W2[idx]);
    } else if (bid < EB + K1 + 256 + HB) {
        hist[t] = 0;
        __syncthreads();
        int n = (bid - EB - K1 - 256) * 256 + t;
        if (n < N) atomicAdd(&hist[batch[n]], 1);
        __syncthreads();
        if (hist[t] != 0) atomicAdd(&cnt[t], hist[t]);
    } else {  // x -> excess-8 uint4 (64B rows) + scaleRaw = rowmax/7
        int node = (bid - EB - K1 - 256 - HB) * 4 + (t >> 6);
        int lane = t & 63;
        if (node < N) {
            float2 v = reinterpret_cast<const float2*>(x)[(size_t)node * 64 + lane];
            float m = fmaxf(fabsf(v.x), fabsf(v.y));
            #pragma unroll
            for (int d = 32; d >= 1; d >>= 1) m = fmaxf(m, __shfl_xor(m, d, 64));
            float qinv = m > 0.f ? 7.f / m : 0.f;
            int q0 = min(max((int)rintf(v.x * qinv) + 8, 0), 15);
            int q1 = min(max((int)rintf(v.y * qinv) + 8, 0), 15);
            Y0q[(size_t)node * 64 + lane] = (unsigned char)(q0 | (q1 << 4));
            if (lane == 0) scaleRaw[node] = m * (1.f / 7.f);
        }
    }
}

// ---------------- CSR build pass 2 (per-bucket counting sort) --------------
__global__ __launch_bounds__(256) void fine_place_kernel(
        const unsigned* __restrict__ pairs, const int* __restrict__ bucketCnt,
        int* __restrict__ off, float* __restrict__ dinv,
        const float* __restrict__ scaleRaw, float* __restrict__ scale0,
        int* __restrict__ csr, int N, int E) {
    __shared__ int hist[256];
    __shared__ int loff[256];
    __shared__ int ws[4];
    __shared__ int sbase;
    int b = blockIdx.x, t = threadIdx.x;
    int lane = t & 63, w = t >> 6;

    int part = 0;
    for (int i = t; i < b; i += 256) part += bucketCnt[i];
    #pragma unroll
    for (int d = 1; d < 64; d <<= 1) part += __shfl_xor(part, d, 64);
    if (lane == 0) ws[w] = part;
    __syncthreads();
    if (t == 0) sbase = ws[0] + ws[1] + ws[2] + ws[3];
    if (b == 0 && t == 0) off[N] = E;
    __syncthreads();
    int base = sbase;

    int cnt = min(bucketCnt[b], BCAP);
    const unsigned* pp = pairs + (size_t)b * BCAP;
    hist[t] = 0;
    __syncthreads();
    for (int i = t; i < cnt; i += 256) atomicAdd(&hist[pp[i] >> 24], 1);
    __syncthreads();
    int v = hist[t];
    {
        int x = v;
        #pragma unroll
        for (int d = 1; d < 64; d <<= 1) {
            int y = __shfl_up(x, d, 64);
            if (lane >= d) x += y;
        }
        if (lane == 63) ws[w] = x;
        __syncthreads();
        int woff = 0;
        #pragma unroll
        for (int j = 0; j < 4; j++)
            if (j < w) woff += ws[j];
        loff[t] = woff + x - v;
    }
    int node = b * 256 + t;
    if (node < N) {
        off[node] = base + loff[t];
        float di = rsqrtf((float)v + 1.0f);
        dinv[node] = di;
        scale0[node] = di * scaleRaw[node];
    }
    __syncthreads();
    hist[t] = 0;
    __syncthreads();
    for (int i = t; i < cnt; i += 256) {
        unsigned pr = pp[i];
        int dl = pr >> 24;
        int r = atomicAdd(&hist[dl], 1);
        csr[base + loff[dl] + r] = (int)(pr & 0xFFFFFFu);
    }
}

// ---------------- aggregate bodies (device) ----------------

__device__ __forceinline__ void agg_q4x_body(
        const unsigned char* __restrict__ Q, const float* __restrict__ scale,
        unsigned short* __restrict__ OUT,
        const int* __restrict__ off, const int* __restrict__ csr,
        const float* __restrict__ dinv, int node, int lane) {
    float acc0, acc1, ssum;
    auto loadpay = [&](int s) -> unsigned { return (unsigned)Q[(size_t)s * 64 + lane]; };
    auto lo = [&](unsigned b) -> float { return (float)(b & 15u); };
    auto hi = [&](unsigned b) -> float { return (float)((b >> 4) & 15u); };
    {
        unsigned v = loadpay(node);
        float sc = scale[node];
        acc0 = sc * lo(v); acc1 = sc * hi(v); ssum = sc;
    }
    int e0 = off[node], e1 = off[node + 1];
    int e = e0;
    for (; e + 16 <= e1; e += 16) {
        int s[16]; unsigned v[16]; float sc[16];
        #pragma unroll
        for (int j = 0; j < 16; j++) s[j] = csr[e + j];
        #pragma unroll
        for (int j = 0; j < 16; j++) { v[j] = loadpay(s[j]); sc[j] = scale[s[j]]; }
        #pragma unroll
        for (int j = 0; j < 16; j++) { ssum += sc[j]; acc0 += sc[j] * lo(v[j]); acc1 += sc[j] * hi(v[j]); }
    }
    if (e + 8 <= e1) {
        int s[8]; unsigned v[8]; float sc[8];
        #pragma unroll
        for (int j = 0; j < 8; j++) s[j] = csr[e + j];
        #pragma unroll
        for (int j = 0; j < 8; j++) { v[j] = loadpay(s[j]); sc[j] = scale[s[j]]; }
        #pragma unroll
        for (int j = 0; j < 8; j++) { ssum += sc[j]; acc0 += sc[j] * lo(v[j]); acc1 += sc[j] * hi(v[j]); }
        e += 8;
    }
    for (; e < e1; e++) {
        int s = csr[e];
        unsigned v = loadpay(s);
        float sc = scale[s];
        ssum += sc; acc0 += sc * lo(v); acc1 += sc * hi(v);
    }
    float corr = 8.f * ssum;
    float di = dinv[node];
    unsigned o = (unsigned)f2bf(di * (acc0 - corr)) |
                 ((unsigned)f2bf(di * (acc1 - corr)) << 16);
    reinterpret_cast<unsigned*>(OUT)[(size_t)node * 64 + lane] = o;
}

__device__ __forceinline__ void agg_q4_body(
        const unsigned short* __restrict__ Q4, const float* __restrict__ scale,
        unsigned short* __restrict__ OUT,
        const int* __restrict__ off, const int* __restrict__ csr,
        const float* __restrict__ dinv, int node, int lane) {
    float acc[4];
    auto loadpay = [&](int s) -> unsigned { return (unsigned)Q4[(size_t)s * 64 + lane]; };
    {
        unsigned u = nibexp(loadpay(node));
        float sc = scale[node];
        #pragma unroll
        for (int q = 0; q < 4; q++) acc[q] = sc * ub(u, q);
    }
    int e0 = off[node], e1 = off[node + 1];
    int e = e0;
    for (; e + 16 <= e1; e += 16) {
        int s[16]; unsigned v[16]; float sc[16];
        #pragma unroll
        for (int j = 0; j < 16; j++) s[j] = csr[e + j];
        #pragma unroll
        for (int j = 0; j < 16; j++) { v[j] = loadpay(s[j]); sc[j] = scale[s[j]]; }
        #pragma unroll
        for (int j = 0; j < 16; j++) {
            unsigned u = nibexp(v[j]);
            #pragma unroll
            for (int q = 0; q < 4; q++) acc[q] += sc[j] * ub(u, q);
        }
    }
    if (e + 8 <= e1) {
        int s[8]; unsigned v[8]; float sc[8];
        #pragma unroll
        for (int j = 0; j < 8; j++) s[j] = csr[e + j];
        #pragma unroll
        for (int j = 0; j < 8; j++) { v[j] = loadpay(s[j]); sc[j] = scale[s[j]]; }
        #pragma unroll
        for (int j = 0; j < 8; j++) {
            unsigned u = nibexp(v[j]);
            #pragma unroll
            for (int q = 0; q < 4; q++) acc[q] += sc[j] * ub(u, q);
        }
        e += 8;
    }
    for (; e < e1; e++) {
        int s = csr[e];
        unsigned u = nibexp(loadpay(s));
        float sc = scale[s];
        #pragma unroll
        for (int q = 0; q < 4; q++) acc[q] += sc * ub(u, q);
    }
    float di = dinv[node];
    uint2 o;
    o.x = (unsigned)f2bf(di * acc[0]) | ((unsigned)f2bf(di * acc[1]) << 16);
    o.y = (unsigned)f2bf(di * acc[2]) | ((unsigned)f2bf(di * acc[3]) << 16);
    reinterpret_cast<uint2*>(OUT)[(size_t)node * 64 + lane] = o;
}

// ---------------- GEMM body (device): 64x256 tile ----------------
// BREG: W^T in registers (solo kernels) vs loaded from L2 (fused, VGPR<=128).
template <int K, int MODE, bool BREG>
__device__ __forceinline__ void gemm_body(
        const unsigned short* __restrict__ A, const unsigned short* __restrict__ WT,
        const float* __restrict__ bias, const float* __restrict__ dinv,
        char* __restrict__ Cq, float* __restrict__ scaleOut,
        const int* __restrict__ batch, float* __restrict__ gsum,
        int M, int r0, char* As, char* extra) {
    constexpr int KK = K / 32;
    constexpr int RB = K * 2;
    constexpr int CHUNKS = 64 * RB / 16;
    const int t = threadIdx.x;
    const int lane = t & 63, w = t >> 6;
    const int lhi = lane >> 4, l15 = lane & 15;

    auto bload = [&](int nf, int kk) -> bf16x8 {
        return *reinterpret_cast<const bf16x8*>(
            WT + (size_t)(w * 64 + nf * 16 + l15) * K + kk * 32 + lhi * 8);
    };
    bf16x8 breg[4][KK];
    if constexpr (BREG) {
        #pragma unroll
        for (int nf = 0; nf < 4; nf++)
            #pragma unroll
            for (int kk = 0; kk < KK; kk++) breg[nf][kk] = bload(nf, kk);
    }
    float bn[4];
    #pragma unroll
    for (int nf = 0; nf < 4; nf++) bn[nf] = bias[w * 64 + nf * 16 + l15];

    #pragma unroll
    for (int p = 0; p < CHUNKS / 256; p++) {
        int idx = p * 256 + t;
        int row = idx / (RB / 16);
        int cb = idx % (RB / 16);
        int sbyte = (cb * 16) ^ ((row & 7) << 4);
        const char* g = (const char*)(A + (size_t)(r0 + row) * K) + sbyte;
        __builtin_amdgcn_global_load_lds(
            (const __attribute__((address_space(1))) void*)g,
            (__attribute__((address_space(3))) void*)(As + idx * 16),
            16, 0, 0);
    }
    __syncthreads();

    f32x4 acc[4][4];
    #pragma unroll
    for (int i = 0; i < 4; i++)
        #pragma unroll
        for (int j = 0; j < 4; j++) acc[i][j] = (f32x4){0.f, 0.f, 0.f, 0.f};

    #pragma unroll
    for (int kk = 0; kk < KK; kk++) {
        bf16x8 a[4];
        int kb = (kk * 32 + lhi * 8) * 2;
        #pragma unroll
        for (int mf = 0; mf < 4; mf++) {
            int row = mf * 16 + l15;
            a[mf] = *reinterpret_cast<const bf16x8*>(
                As + row * RB + (kb ^ ((row & 7) << 4)));
        }
        #pragma unroll
        for (int mf = 0; mf < 4; mf++)
            #pragma unroll
            for (int nf = 0; nf < 4; nf++) {
                bf16x8 bv;
                if constexpr (BREG) bv = breg[nf][kk];
                else bv = bload(nf, kk);
                acc[mf][nf] = __builtin_amdgcn_mfma_f32_16x16x32_bf16(
                    a[mf], bv, acc[mf][nf], 0, 0, 0);
            }
    }

    if constexpr (MODE == 0) {
        float* wmax = (float*)extra;
        float* qinv = wmax + 256;
        char* pack = (char*)(qinv + 64);
        #pragma unroll
        for (int mf = 0; mf < 4; mf++)
            #pragma unroll
            for (int j = 0; j < 4; j++) {
                float lmax = 0.f;
                #pragma unroll
                for (int nf = 0; nf < 4; nf++) {
                    float v = fmaxf(acc[mf][nf][j] + bn[nf], 0.f);
                    acc[mf][nf][j] = v;
                    lmax = fmaxf(lmax, v);
                }
                lmax = fmaxf(lmax, __shfl_xor(lmax, 1, 64));
                lmax = fmaxf(lmax, __shfl_xor(lmax, 2, 64));
                lmax = fmaxf(lmax, __shfl_xor(lmax, 4, 64));
                lmax = fmaxf(lmax, __shfl_xor(lmax, 8, 64));
                if (l15 == 0) wmax[w * 64 + mf * 16 + lhi * 4 + j] = lmax;
            }
        __syncthreads();
        if (t < 64) {
            float m4 = fmaxf(fmaxf(wmax[t], wmax[64 + t]),
                             fmaxf(wmax[128 + t], wmax[192 + t]));
            qinv[t] = m4 > 0.f ? 15.f / m4 : 0.f;
            if (r0 + t < M) scaleOut[r0 + t] = dinv[r0 + t] * m4 * (1.f / 15.f);
        }
        __syncthreads();
        #pragma unroll
        for (int mf = 0; mf < 4; mf++)
            #pragma unroll
            for (int j = 0; j < 4; j++) {
                int r = mf * 16 + lhi * 4 + j;
                float qi = qinv[r];
                #pragma unroll
                for (int nf = 0; nf < 4; nf++)
                    pack[r * 256 + w * 64 + nf * 16 + l15] =
                        (char)min((int)rintf(acc[mf][nf][j] * qi), 15);
            }
        __syncthreads();
        #pragma unroll
        for (int p = 0; p < 4; p++) {
            int idx = p * 256 + t;
            uint4 s4 = reinterpret_cast<const uint4*>(pack)[idx];
            uint2 o;
            o.x = nib4(s4.x) | (nib4(s4.y) << 16);
            o.y = nib4(s4.z) | (nib4(s4.w) << 16);
            reinterpret_cast<uint2*>(Cq + (size_t)r0 * 128)[idx] = o;
        }
    } else {
        int gmin = batch[min(r0, M - 1)];
        int gmax = batch[min(r0 + 63, M - 1)];
        if (gmin == gmax) {
            #pragma unroll
            for (int nf = 0; nf < 4; nf++) {
                float s = 0.f;
                #pragma unroll
                for (int mf = 0; mf < 4; mf++)
                    #pragma unroll
                    for (int j = 0; j < 4; j++) {
                        int m = r0 + mf * 16 + lhi * 4 + j;
                        float v = fmaxf(acc[mf][nf][j] + bn[nf], 0.f);
                        s += (m < M) ? v : 0.f;
                    }
                s += __shfl_xor(s, 16, 64);
                s += __shfl_xor(s, 32, 64);
                if (lhi == 0)
                    atomicAdd(&gsum[(size_t)gmin * 256 + w * 64 + nf * 16 + l15], s);
            }
        } else {
            #pragma unroll
            for (int mf = 0; mf < 4; mf++)
                #pragma unroll
                for (int j = 0; j < 4; j++) {
                    int m = r0 + mf * 16 + lhi * 4 + j;
                    if (m < M) {
                        int g = batch[m];
                        #pragma unroll
                        for (int nf = 0; nf < 4; nf++)
                            atomicAdd(&gsum[(size_t)g * 256 + w * 64 + nf * 16 + l15],
                                      fmaxf(acc[mf][nf][j] + bn[nf], 0.f));
                    }
                }
        }
    }
}

// ---------------- standalone kernels (solo chunks; full occupancy) ---------

__global__ __launch_bounds__(256) void aggregate_q4x_kernel(
        const unsigned char* __restrict__ Q, const float* __restrict__ scale,
        unsigned short* __restrict__ OUT,
        const int* __restrict__ off, const int* __restrict__ csr,
        const float* __restrict__ dinv, int nodeStart, int nodeEnd) {
    int node = __builtin_amdgcn_readfirstlane(nodeStart + blockIdx.x * 4 + (threadIdx.x >> 6));
    if (node < nodeEnd)
        agg_q4x_body(Q, scale, OUT, off, csr, dinv, node, threadIdx.x & 63);
}

__global__ __launch_bounds__(256) void aggregate_q4_kernel(
        const unsigned short* __restrict__ Q4, const float* __restrict__ scale,
        unsigned short* __restrict__ OUT,
        const int* __restrict__ off, const int* __restrict__ csr,
        const float* __restrict__ dinv, int nodeStart, int nodeEnd) {
    int node = __builtin_amdgcn_readfirstlane(nodeStart + blockIdx.x * 4 + (threadIdx.x >> 6));
    if (node < nodeEnd)
        agg_q4_body(Q4, scale, OUT, off, csr, dinv, node, threadIdx.x & 63);
}

template <int K, int MODE>
__global__ __launch_bounds__(256) void mfma_gemm_kernel(
        const unsigned short* __restrict__ A, const unsigned short* __restrict__ WT,
        const float* __restrict__ bias, const float* __restrict__ dinv,
        char* __restrict__ Cq, float* __restrict__ scaleOut,
        const int* __restrict__ batch, float* __restrict__ gsum, int M, int rowStart) {
    __shared__ __align__(16) char As[64 * K * 2];
    __shared__ __align__(16) char extra[(MODE == 0) ? (256 * 4 + 64 * 4 + 64 * 256) : 16];
    gemm_body<K, MODE, true>(A, WT, bias, dinv, Cq, scaleOut, batch, gsum,
                             M, rowStart + blockIdx.x * 64, As, extra);
}

// ---------------- fused role-split kernels (agg chunk c+1 || GEMM chunk c) --
// Role interleave: every 17th block is a GEMM block (co-residency).
__device__ __forceinline__ bool role_split(int bid, int G, int& gemmIdx, int& aggIdx) {
    if (bid % 17 == 0 && bid / 17 < G) { gemmIdx = bid / 17; return true; }
    aggIdx = bid - min((bid + 16) / 17, G);
    return false;
}

__global__ __launch_bounds__(256, 4) void fused_l1_kernel(
        const unsigned char* __restrict__ Q0, const float* __restrict__ scale0,
        unsigned short* __restrict__ a1,
        const int* __restrict__ off, const int* __restrict__ csr,
        const float* __restrict__ dinv,
        const unsigned short* __restrict__ WT1, const float* __restrict__ b1,
        char* __restrict__ Y1q4, float* __restrict__ scale1,
        int N, int gemmTiles, int aggStart, int aggEnd, int gemmStart) {
    __shared__ __align__(16) char As[64 * 256];
    __shared__ __align__(16) char extra[256 * 4 + 64 * 4 + 64 * 256];
    int gi, ai;
    if (role_split(blockIdx.x, gemmTiles, gi, ai)) {
        gemm_body<128, 0, false>(a1, WT1, b1, dinv, Y1q4, scale1, nullptr, nullptr,
                                 N, gemmStart + gi * 64, As, extra);
    } else {
        int node = __builtin_amdgcn_readfirstlane(aggStart + ai * 4 + (threadIdx.x >> 6));
        if (node < aggEnd)
            agg_q4x_body(Q0, scale0, a1, off, csr, dinv, node, threadIdx.x & 63);
    }
}

__global__ __launch_bounds__(256, 4) void fused_l2_kernel(
        const unsigned short* __restrict__ Y1q4, const float* __restrict__ scale1,
        unsigned short* __restrict__ a2,
        const int* __restrict__ off, const int* __restrict__ csr,
        const float* __restrict__ dinv,
        const unsigned short* __restrict__ WT2, const float* __restrict__ b2,
        const int* __restrict__ batch, float* __restrict__ gsum,
        int N, int gemmTiles, int aggStart, int aggEnd, int gemmStart) {
    __shared__ __align__(16) char As[64 * 512];
    __shared__ __align__(16) char extra[16];
    int gi, ai;
    if (role_split(blockIdx.x, gemmTiles, gi, ai)) {
        gemm_body<256, 1, false>(a2, WT2, b2, nullptr, nullptr, nullptr, batch, gsum,
                                 N, gemmStart + gi * 64, As, extra);
    } else {
        int node = __builtin_amdgcn_readfirstlane(aggStart + ai * 4 + (threadIdx.x >> 6));
        if (node < aggEnd)
            agg_q4_body(Y1q4, scale1, a2, off, csr, dinv, node, threadIdx.x & 63);
    }
}

// ---------------- final pool-divide + classifier head ----------------
__global__ __launch_bounds__(256) void pool_final_kernel(const float* __restrict__ gsum,
                                                         const int* __restrict__ cnt,
                                                         const float* __restrict__ Wc,
                                                         const float* __restrict__ bc,
                                                         float* __restrict__ out) {
    __shared__ float gm[256];
    int g = blockIdx.x, t = threadIdx.x;
    float inv = 1.0f / fmaxf((float)cnt[g], 1.0f);
    gm[t] = gsum[g * 256 + t] * inv;
    __syncthreads();
    if (t < 200) {
        float acc = bc[t];
        #pragma unroll 8
        for (int k = 0; k < 256; k++) acc += gm[k] * Wc[k * 200 + t];
        out[g * 200 + t] = acc;
    }
}

// ---------------- driver ----------------
extern "C" void kernel_launch(void* const* d_in, const int* in_sizes, int n_in,
                              void* d_out, int out_size, void* d_ws, size_t ws_size,
                              hipStream_t stream) {
    const float* x   = (const float*)d_in[0];
    const int* ei    = (const int*)d_in[1];
    const int* batch = (const int*)d_in[2];
    const float* W1  = (const float*)d_in[4];
    const float* b1  = (const float*)d_in[5];
    const float* W2  = (const float*)d_in[6];
    const float* b2  = (const float*)d_in[7];
    const float* Wc  = (const float*)d_in[8];
    const float* bc  = (const float*)d_in[9];
    float* out = (float*)d_out;

    const int N = in_sizes[2];       // 100000
    const int E = in_sizes[1] / 2;   // 1600000
    const int G = out_size / 200;    // 64
    const int K1 = in_sizes[0] / N;  // 128
    const int Mpad = (N + 63) & ~63; // 100032
    const int NB = (N + 255) >> 8;   // 391
    const int ntiles = Mpad / 64;    // 1563
    const int EB = (E + P1_CHUNK - 1) / P1_CHUNK;
    const int* src = ei;
    const int* dst = ei + E;

    char* p = (char*)d_ws;
    auto alloc = [&](size_t bytes) -> char* {
        char* r = p;
        p += (bytes + 255) & ~(size_t)255;
        return r;
    };
    int*   off      = (int*)alloc((size_t)(N + 1) * 4);
    int*   bktCnt   = (int*)alloc((size_t)NB * 4);
    int*   cnt      = (int*)alloc(256 * 4);
    float* dinv     = (float*)alloc((size_t)N * 4);
    float* scaleRaw = (float*)alloc((size_t)N * 4);
    float* scale0   = (float*)alloc((size_t)N * 4);
    float* scale1   = (float*)alloc((size_t)N * 4);
    float* gsum     = (float*)alloc((size_t)G * 256 * 4);
    int*   csr      = (int*)alloc((size_t)E * 4);
    unsigned* pairs = (unsigned*)alloc((size_t)NB * BCAP * 4);
    unsigned short* WT1 = (unsigned short*)alloc((size_t)256 * K1 * 2);
    unsigned short* WT2 = (unsigned short*)alloc((size_t)256 * 256 * 2);
    unsigned char*  Y0q4 = (unsigned char*)alloc((size_t)N * 64);
    char*           Y1q4 = alloc((size_t)Mpad * 128);
    unsigned short* a1   = (unsigned short*)alloc((size_t)Mpad * K1 * 2);
    unsigned short* a2   = (unsigned short*)alloc((size_t)Mpad * 256 * 2);

    hipMemsetAsync(bktCnt, 0, (size_t)NB * 4, stream);
    hipMemsetAsync(cnt, 0, 256 * 4, stream);
    hipMemsetAsync(gsum, 0, (size_t)G * 256 * 4, stream);

    int blkN = (N + 255) / 256;
    int PB = (N + 3) / 4;
    scatter_prep_kernel<<<EB + K1 + 256 + blkN + PB, 256, 0, stream>>>(
        src, dst, bktCnt, pairs, E, NB, EB, W1, WT1, K1, W2, WT2,
        batch, cnt, N, blkN, x, Y0q4, scaleRaw);
    fine_place_kernel<<<NB, 256, 0, stream>>>(
        pairs, bktCnt, off, dinv, scaleRaw, scale0, csr, N, E);

    // 3-chunk pipeline: agg(c+1) co-scheduled with GEMM(c)
    const int CT = ntiles / 3;              // 521
    const int RC = CT * 64;                 // 33344
    const int T2 = ntiles - 2 * CT;         // last chunk tiles
    int end0 = min(RC, N), end1 = min(2 * RC, N);
    int ab0 = (end0 + 3) / 4;
    int ab1 = (end1 - RC + 3) / 4;
    int ab2 = (N - 2 * RC + 3) / 4;

    // ---- layer 1 ----
    aggregate_q4x_kernel<<<ab0, 256, 0, stream>>>(Y0q4, scale0, a1, off, csr, dinv, 0, end0);
    fused_l1_kernel<<<ab1 + CT, 256, 0, stream>>>(
        Y0q4, scale0, a1, off, csr, dinv, WT1, b1, Y1q4, scale1,
        N, CT, RC, end1, 0);
    fused_l1_kernel<<<ab2 + CT, 256, 0, stream>>>(
        Y0q4, scale0, a1, off, csr, dinv, WT1, b1, Y1q4, scale1,
        N, CT, 2 * RC, N, RC);
    mfma_gemm_kernel<128, 0><<<T2, 256, 0, stream>>>(
        a1, WT1, b1, dinv, Y1q4, scale1, nullptr, nullptr, N, 2 * RC);

    // ---- layer 2 ----
    aggregate_q4_kernel<<<ab0, 256, 0, stream>>>(
        (const unsigned short*)Y1q4, scale1, a2, off, csr, dinv, 0, end0);
    fused_l2_kernel<<<ab1 + CT, 256, 0, stream>>>(
        (const unsigned short*)Y1q4, scale1, a2, off, csr, dinv, WT2, b2,
        batch, gsum, N, CT, RC, end1, 0);
    fused_l2_kernel<<<ab2 + CT, 256, 0, stream>>>(
        (const unsigned short*)Y1q4, scale1, a2, off, csr, dinv, WT2, b2,
        batch, gsum, N, CT, 2 * RC, N, RC);
    mfma_gemm_kernel<256, 1><<<T2, 256, 0, stream>>>(
        a2, WT2, b2, nullptr, nullptr, nullptr, batch, gsum, N, 2 * RC);

    // ---- head ----
    pool_final_kernel<<<G, 256, 0, stream>>>(gsum, cnt, Wc, bc, out);
}

// Round 16
// 263.062 us; speedup vs baseline: 1.3670x; 1.3670x over previous
//
#include <hip/hip_runtime.h>
#include <cstdint>
#include <cstddef>

// ---------------------------------------------------------------------------
// WindowGCN: 2-layer GCN + mean-pool + linear head.
// R16: revert to R14 (R15's role-split fusion shared the GEMM's 32KB-LDS
//      envelope with the agg role -> gather occupancy collapsed 68->21%).
//      R14 = gathers at compulsory-miss floor (uint4 tables, FETCH = 8 XCD x
//      table), one-tile-per-block MFMA GEMMs (reg W^T, swizzled
//      global_load_lds), 2-level bucket CSR, fused mean-pool epilogue.
//      New in R16: single merged memset (bktCnt|cnt|gsum contiguous).
// ---------------------------------------------------------------------------

typedef __attribute__((ext_vector_type(8))) short bf16x8;
typedef __attribute__((ext_vector_type(4))) float f32x4;

#define P1_CHUNK 4096
#define BCAP 8192  // pairs capacity per 256-node bucket (mean 4093)

__device__ inline unsigned short f2bf(float f) {  // RNE fp32 -> bf16
    unsigned u = __float_as_uint(f);
    u = (u + 0x7FFFu + ((u >> 16) & 1u)) >> 16;
    return (unsigned short)u;
}
__device__ inline unsigned nib4(unsigned u) {  // 4 bytes (0..15) -> 4 nibbles
    return (u & 15u) | (((u >> 8) & 15u) << 4) | (((u >> 16) & 15u) << 8) |
           (((u >> 24) & 15u) << 12);
}
__device__ inline unsigned nibexp(unsigned h) {  // 4 nibbles -> 4 bytes
    unsigned t = (h | (h << 8)) & 0x00FF00FFu;
    return (t | (t << 4)) & 0x0F0F0F0Fu;
}
// (float)((u >> 8*q) & 255) lowers to v_cvt_f32_ubyte{q}
__device__ inline float ub(unsigned u, int q) { return (float)((u >> (8 * q)) & 255u); }

// ------- merged prep: bucket scatter | W transposes | graph hist | x->q4 ----
__global__ __launch_bounds__(256) void scatter_prep_kernel(
        const int* __restrict__ src, const int* __restrict__ dst,
        int* __restrict__ bucketCnt, unsigned* __restrict__ pairs, int E, int NB, int EB,
        const float* __restrict__ W1, unsigned short* __restrict__ WT1, int K1,
        const float* __restrict__ W2, unsigned short* __restrict__ WT2,
        const int* __restrict__ batch, int* __restrict__ cnt, int N, int HB,
        const float* __restrict__ x, unsigned char* __restrict__ Y0q,
        float* __restrict__ scaleRaw) {
    __shared__ int hist[512];
    __shared__ int base[512];
    int bid = blockIdx.x, t = threadIdx.x;
    if (bid < EB) {  // bucket scatter: pairs packed u32 = src | dst_local<<24
        int e0 = bid * P1_CHUNK;
        int eend = min(e0 + P1_CHUNK, E);
        for (int i = t; i < NB; i += 256) hist[i] = 0;
        __syncthreads();
        for (int e = e0 + t; e < eend; e += 256) atomicAdd(&hist[dst[e] >> 8], 1);
        __syncthreads();
        for (int i = t; i < NB; i += 256) {
            int c = hist[i];
            base[i] = (c > 0) ? atomicAdd(&bucketCnt[i], c) : 0;
            hist[i] = 0;  // reuse as cursor
        }
        __syncthreads();
        for (int e = e0 + t; e < eend; e += 256) {
            int d = dst[e], s = src[e];
            int b = d >> 8;
            int r = base[b] + atomicAdd(&hist[b], 1);
            if (r < BCAP)
                pairs[(size_t)b * BCAP + r] = (unsigned)s | ((unsigned)(d & 255) << 24);
        }
    } else if (bid < EB + K1) {  // W1 [K1][256] -> WT1 [256][K1]
        int idx = (bid - EB) * 256 + t;
        int k = idx >> 8, n = idx & 255;
        WT1[n * K1 + k] = f2bf(W1[idx]);
    } else if (bid < EB + K1 + 256) {  // W2 -> WT2
        int idx = (bid - EB - K1) * 256 + t;
        int k = idx >> 8, n = idx & 255;
        WT2[n * 256 + k] = f2bf(W2[idx]);
    } else if (bid < EB + K1 + 256 + HB) {  // graph histogram
        hist[t] = 0;
        __syncthreads();
        int n = (bid - EB - K1 - 256) * 256 + t;
        if (n < N) atomicAdd(&hist[batch[n]], 1);
        __syncthreads();
        if (hist[t] != 0) atomicAdd(&cnt[t], hist[t]);
    } else {  // x [N][128] f32 -> excess-8 uint4 (64B rows) + scaleRaw=rowmax/7
        int node = (bid - EB - K1 - 256 - HB) * 4 + (t >> 6);
        int lane = t & 63;
        if (node < N) {
            float2 v = reinterpret_cast<const float2*>(x)[(size_t)node * 64 + lane];
            float m = fmaxf(fabsf(v.x), fabsf(v.y));
            #pragma unroll
            for (int d = 32; d >= 1; d >>= 1) m = fmaxf(m, __shfl_xor(m, d, 64));
            float qinv = m > 0.f ? 7.f / m : 0.f;
            int q0 = min(max((int)rintf(v.x * qinv) + 8, 0), 15);
            int q1 = min(max((int)rintf(v.y * qinv) + 8, 0), 15);
            Y0q[(size_t)node * 64 + lane] = (unsigned char)(q0 | (q1 << 4));
            if (lane == 0) scaleRaw[node] = m * (1.f / 7.f);
        }
    }
}

// ---------------- CSR build pass 2 (per-bucket counting sort) --------------
// Also emits dinv and scale0 = dinv * scaleRaw (layer-1 gather scale).
__global__ __launch_bounds__(256) void fine_place_kernel(
        const unsigned* __restrict__ pairs, const int* __restrict__ bucketCnt,
        int* __restrict__ off, float* __restrict__ dinv,
        const float* __restrict__ scaleRaw, float* __restrict__ scale0,
        int* __restrict__ csr, int N, int E) {
    __shared__ int hist[256];
    __shared__ int loff[256];
    __shared__ int ws[4];
    __shared__ int sbase;
    int b = blockIdx.x, t = threadIdx.x;
    int lane = t & 63, w = t >> 6;

    int part = 0;
    for (int i = t; i < b; i += 256) part += bucketCnt[i];
    #pragma unroll
    for (int d = 1; d < 64; d <<= 1) part += __shfl_xor(part, d, 64);
    if (lane == 0) ws[w] = part;
    __syncthreads();
    if (t == 0) sbase = ws[0] + ws[1] + ws[2] + ws[3];
    if (b == 0 && t == 0) off[N] = E;
    __syncthreads();
    int base = sbase;

    int cnt = min(bucketCnt[b], BCAP);
    const unsigned* pp = pairs + (size_t)b * BCAP;
    hist[t] = 0;
    __syncthreads();
    for (int i = t; i < cnt; i += 256) atomicAdd(&hist[pp[i] >> 24], 1);
    __syncthreads();
    int v = hist[t];
    {
        int x = v;
        #pragma unroll
        for (int d = 1; d < 64; d <<= 1) {
            int y = __shfl_up(x, d, 64);
            if (lane >= d) x += y;
        }
        if (lane == 63) ws[w] = x;
        __syncthreads();
        int woff = 0;
        #pragma unroll
        for (int j = 0; j < 4; j++)
            if (j < w) woff += ws[j];
        loff[t] = woff + x - v;
    }
    int node = b * 256 + t;
    if (node < N) {
        off[node] = base + loff[t];
        float di = rsqrtf((float)v + 1.0f);  // +1 self-loop
        dinv[node] = di;
        scale0[node] = di * scaleRaw[node];
    }
    __syncthreads();
    hist[t] = 0;  // cursors
    __syncthreads();
    for (int i = t; i < cnt; i += 256) {
        unsigned pr = pp[i];
        int dl = pr >> 24;
        int r = atomicAdd(&hist[dl], 1);
        csr[base + loff[dl] + r] = (int)(pr & 0xFFFFFFu);
    }
}

// ---- layer-1 aggregation from uint4 x-table (64B rows, 6.4MB L2-friendly) --
__global__ __launch_bounds__(256) void aggregate_q4x_kernel(
        const unsigned char* __restrict__ Q, const float* __restrict__ scale,
        unsigned short* __restrict__ OUT,
        const int* __restrict__ off, const int* __restrict__ csr,
        const float* __restrict__ dinv, int N) {
    int node = __builtin_amdgcn_readfirstlane(blockIdx.x * 4 + (threadIdx.x >> 6));
    int lane = threadIdx.x & 63;
    if (node >= N) return;

    float acc0, acc1, ssum;
    auto loadpay = [&](int s) -> unsigned {
        return (unsigned)Q[(size_t)s * 64 + lane];
    };
    auto lo = [&](unsigned b) -> float { return (float)(b & 15u); };
    auto hi = [&](unsigned b) -> float { return (float)((b >> 4) & 15u); };
    {
        unsigned v = loadpay(node);
        float sc = scale[node];
        acc0 = sc * lo(v);
        acc1 = sc * hi(v);
        ssum = sc;
    }
    int e0 = off[node], e1 = off[node + 1];
    int e = e0;
    for (; e + 16 <= e1; e += 16) {
        int s[16]; unsigned v[16]; float sc[16];
        #pragma unroll
        for (int j = 0; j < 16; j++) s[j] = csr[e + j];
        #pragma unroll
        for (int j = 0; j < 16; j++) { v[j] = loadpay(s[j]); sc[j] = scale[s[j]]; }
        #pragma unroll
        for (int j = 0; j < 16; j++) {
            ssum += sc[j];
            acc0 += sc[j] * lo(v[j]);
            acc1 += sc[j] * hi(v[j]);
        }
    }
    if (e + 8 <= e1) {
        int s[8]; unsigned v[8]; float sc[8];
        #pragma unroll
        for (int j = 0; j < 8; j++) s[j] = csr[e + j];
        #pragma unroll
        for (int j = 0; j < 8; j++) { v[j] = loadpay(s[j]); sc[j] = scale[s[j]]; }
        #pragma unroll
        for (int j = 0; j < 8; j++) {
            ssum += sc[j];
            acc0 += sc[j] * lo(v[j]);
            acc1 += sc[j] * hi(v[j]);
        }
        e += 8;
    }
    for (; e < e1; e++) {
        int s = csr[e];
        unsigned v = loadpay(s);
        float sc = scale[s];
        ssum += sc;
        acc0 += sc * lo(v);
        acc1 += sc * hi(v);
    }
    float corr = 8.f * ssum;
    float di = dinv[node];
    unsigned o = (unsigned)f2bf(di * (acc0 - corr)) |
                 ((unsigned)f2bf(di * (acc1 - corr)) << 16);
    reinterpret_cast<unsigned*>(OUT)[(size_t)node * 64 + lane] = o;
}

// ------ layer-2 aggregation from UINT4 table (128B rows) ------
__global__ __launch_bounds__(256) void aggregate_q4_kernel(
        const unsigned short* __restrict__ Q4, const float* __restrict__ scale,
        unsigned short* __restrict__ OUT,
        const int* __restrict__ off, const int* __restrict__ csr,
        const float* __restrict__ dinv, int N) {
    int node = __builtin_amdgcn_readfirstlane(blockIdx.x * 4 + (threadIdx.x >> 6));
    int lane = threadIdx.x & 63;
    if (node >= N) return;

    float acc[4];
    auto loadpay = [&](int s) -> unsigned {
        return (unsigned)Q4[(size_t)s * 64 + lane];
    };
    {
        unsigned u = nibexp(loadpay(node));
        float sc = scale[node];
        #pragma unroll
        for (int q = 0; q < 4; q++) acc[q] = sc * ub(u, q);
    }
    int e0 = off[node], e1 = off[node + 1];
    int e = e0;
    for (; e + 16 <= e1; e += 16) {
        int s[16]; unsigned v[16]; float sc[16];
        #pragma unroll
        for (int j = 0; j < 16; j++) s[j] = csr[e + j];
        #pragma unroll
        for (int j = 0; j < 16; j++) { v[j] = loadpay(s[j]); sc[j] = scale[s[j]]; }
        #pragma unroll
        for (int j = 0; j < 16; j++) {
            unsigned u = nibexp(v[j]);
            #pragma unroll
            for (int q = 0; q < 4; q++) acc[q] += sc[j] * ub(u, q);
        }
    }
    if (e + 8 <= e1) {
        int s[8]; unsigned v[8]; float sc[8];
        #pragma unroll
        for (int j = 0; j < 8; j++) s[j] = csr[e + j];
        #pragma unroll
        for (int j = 0; j < 8; j++) { v[j] = loadpay(s[j]); sc[j] = scale[s[j]]; }
        #pragma unroll
        for (int j = 0; j < 8; j++) {
            unsigned u = nibexp(v[j]);
            #pragma unroll
            for (int q = 0; q < 4; q++) acc[q] += sc[j] * ub(u, q);
        }
        e += 8;
    }
    for (; e < e1; e++) {
        int s = csr[e];
        unsigned u = nibexp(loadpay(s));
        float sc = scale[s];
        #pragma unroll
        for (int q = 0; q < 4; q++) acc[q] += sc * ub(u, q);
    }
    float di = dinv[node];
    uint2 o;
    o.x = (unsigned)f2bf(di * acc[0]) | ((unsigned)f2bf(di * acc[1]) << 16);
    o.y = (unsigned)f2bf(di * acc[2]) | ((unsigned)f2bf(di * acc[3]) << 16);
    reinterpret_cast<uint2*>(OUT)[(size_t)node * 64 + lane] = o;
}

// ---------------- MFMA GEMM: one 64x256 tile per block ----------------
template <int K, int MODE>
__global__ __launch_bounds__(256) void mfma_gemm_kernel(
        const unsigned short* __restrict__ A, const unsigned short* __restrict__ WT,
        const float* __restrict__ bias, const float* __restrict__ dinv,
        char* __restrict__ Cq, float* __restrict__ scaleOut,
        const int* __restrict__ batch, float* __restrict__ gsum, int M) {
    constexpr int KK = K / 32;
    constexpr int RB = K * 2;
    constexpr int CHUNKS = 64 * RB / 16;
    constexpr int EXTRA = (MODE == 0) ? (256 * 4 + 64 * 4 + 64 * 256) : 16;
    __shared__ __align__(16) char As[64 * RB];
    __shared__ __align__(16) char extra[EXTRA];

    const int t = threadIdx.x;
    const int lane = t & 63, w = t >> 6;
    const int lhi = lane >> 4, l15 = lane & 15;
    const int r0 = blockIdx.x * 64;

    bf16x8 breg[4][KK];
    #pragma unroll
    for (int nf = 0; nf < 4; nf++)
        #pragma unroll
        for (int kk = 0; kk < KK; kk++)
            breg[nf][kk] = *reinterpret_cast<const bf16x8*>(
                WT + (size_t)(w * 64 + nf * 16 + l15) * K + kk * 32 + lhi * 8);
    float bn[4];
    #pragma unroll
    for (int nf = 0; nf < 4; nf++) bn[nf] = bias[w * 64 + nf * 16 + l15];

    #pragma unroll
    for (int p = 0; p < CHUNKS / 256; p++) {
        int idx = p * 256 + t;
        int row = idx / (RB / 16);
        int cb = idx % (RB / 16);
        int sbyte = (cb * 16) ^ ((row & 7) << 4);
        const char* g = (const char*)(A + (size_t)(r0 + row) * K) + sbyte;
        __builtin_amdgcn_global_load_lds(
            (const __attribute__((address_space(1))) void*)g,
            (__attribute__((address_space(3))) void*)(As + idx * 16),
            16, 0, 0);
    }
    __syncthreads();

    f32x4 acc[4][4];
    #pragma unroll
    for (int i = 0; i < 4; i++)
        #pragma unroll
        for (int j = 0; j < 4; j++) acc[i][j] = (f32x4){0.f, 0.f, 0.f, 0.f};

    #pragma unroll
    for (int kk = 0; kk < KK; kk++) {
        bf16x8 a[4];
        int kb = (kk * 32 + lhi * 8) * 2;
        #pragma unroll
        for (int mf = 0; mf < 4; mf++) {
            int row = mf * 16 + l15;
            a[mf] = *reinterpret_cast<const bf16x8*>(
                As + row * RB + (kb ^ ((row & 7) << 4)));
        }
        #pragma unroll
        for (int mf = 0; mf < 4; mf++)
            #pragma unroll
            for (int nf = 0; nf < 4; nf++)
                acc[mf][nf] = __builtin_amdgcn_mfma_f32_16x16x32_bf16(
                    a[mf], breg[nf][kk], acc[mf][nf], 0, 0, 0);
    }

    if constexpr (MODE == 0) {
        float* wmax = (float*)extra;
        float* qinv = wmax + 256;
        char* pack = (char*)(qinv + 64);
        #pragma unroll
        for (int mf = 0; mf < 4; mf++)
            #pragma unroll
            for (int j = 0; j < 4; j++) {
                float lmax = 0.f;
                #pragma unroll
                for (int nf = 0; nf < 4; nf++) {
                    float v = fmaxf(acc[mf][nf][j] + bn[nf], 0.f);
                    acc[mf][nf][j] = v;
                    lmax = fmaxf(lmax, v);
                }
                lmax = fmaxf(lmax, __shfl_xor(lmax, 1, 64));
                lmax = fmaxf(lmax, __shfl_xor(lmax, 2, 64));
                lmax = fmaxf(lmax, __shfl_xor(lmax, 4, 64));
                lmax = fmaxf(lmax, __shfl_xor(lmax, 8, 64));
                if (l15 == 0) wmax[w * 64 + mf * 16 + lhi * 4 + j] = lmax;
            }
        __syncthreads();
        if (t < 64) {
            float m4 = fmaxf(fmaxf(wmax[t], wmax[64 + t]),
                             fmaxf(wmax[128 + t], wmax[192 + t]));
            qinv[t] = m4 > 0.f ? 15.f / m4 : 0.f;
            if (r0 + t < M) scaleOut[r0 + t] = dinv[r0 + t] * m4 * (1.f / 15.f);
        }
        __syncthreads();
        #pragma unroll
        for (int mf = 0; mf < 4; mf++)
            #pragma unroll
            for (int j = 0; j < 4; j++) {
                int r = mf * 16 + lhi * 4 + j;
                float qi = qinv[r];
                #pragma unroll
                for (int nf = 0; nf < 4; nf++)
                    pack[r * 256 + w * 64 + nf * 16 + l15] =
                        (char)min((int)rintf(acc[mf][nf][j] * qi), 15);
            }
        __syncthreads();
        #pragma unroll
        for (int p = 0; p < 4; p++) {
            int idx = p * 256 + t;
            uint4 s4 = reinterpret_cast<const uint4*>(pack)[idx];
            uint2 o;
            o.x = nib4(s4.x) | (nib4(s4.y) << 16);
            o.y = nib4(s4.z) | (nib4(s4.w) << 16);
            reinterpret_cast<uint2*>(Cq + (size_t)r0 * 128)[idx] = o;
        }
    } else {
        int gmin = batch[min(r0, M - 1)];
        int gmax = batch[min(r0 + 63, M - 1)];
        if (gmin == gmax) {
            #pragma unroll
            for (int nf = 0; nf < 4; nf++) {
                float s = 0.f;
                #pragma unroll
                for (int mf = 0; mf < 4; mf++)
                    #pragma unroll
                    for (int j = 0; j < 4; j++) {
                        int m = r0 + mf * 16 + lhi * 4 + j;
                        float v = fmaxf(acc[mf][nf][j] + bn[nf], 0.f);
                        s += (m < M) ? v : 0.f;
                    }
                s += __shfl_xor(s, 16, 64);
                s += __shfl_xor(s, 32, 64);
                if (lhi == 0)
                    atomicAdd(&gsum[(size_t)gmin * 256 + w * 64 + nf * 16 + l15], s);
            }
        } else {
            #pragma unroll
            for (int mf = 0; mf < 4; mf++)
                #pragma unroll
                for (int j = 0; j < 4; j++) {
                    int m = r0 + mf * 16 + lhi * 4 + j;
                    if (m < M) {
                        int g = batch[m];
                        #pragma unroll
                        for (int nf = 0; nf < 4; nf++)
                            atomicAdd(&gsum[(size_t)g * 256 + w * 64 + nf * 16 + l15],
                                      fmaxf(acc[mf][nf][j] + bn[nf], 0.f));
                    }
                }
        }
    }
}

// ---------------- final pool-divide + classifier head ----------------
__global__ __launch_bounds__(256) void pool_final_kernel(const float* __restrict__ gsum,
                                                         const int* __restrict__ cnt,
                                                         const float* __restrict__ Wc,
                                                         const float* __restrict__ bc,
                                                         float* __restrict__ out) {
    __shared__ float gm[256];
    int g = blockIdx.x, t = threadIdx.x;
    float inv = 1.0f / fmaxf((float)cnt[g], 1.0f);
    gm[t] = gsum[g * 256 + t] * inv;
    __syncthreads();
    if (t < 200) {
        float acc = bc[t];
        #pragma unroll 8
        for (int k = 0; k < 256; k++) acc += gm[k] * Wc[k * 200 + t];
        out[g * 200 + t] = acc;
    }
}

// ---------------- driver ----------------
extern "C" void kernel_launch(void* const* d_in, const int* in_sizes, int n_in,
                              void* d_out, int out_size, void* d_ws, size_t ws_size,
                              hipStream_t stream) {
    const float* x   = (const float*)d_in[0];
    const int* ei    = (const int*)d_in[1];
    const int* batch = (const int*)d_in[2];
    const float* W1  = (const float*)d_in[4];
    const float* b1  = (const float*)d_in[5];
    const float* W2  = (const float*)d_in[6];
    const float* b2  = (const float*)d_in[7];
    const float* Wc  = (const float*)d_in[8];
    const float* bc  = (const float*)d_in[9];
    float* out = (float*)d_out;

    const int N = in_sizes[2];       // 100000
    const int E = in_sizes[1] / 2;   // 1600000
    const int G = out_size / 200;    // 64
    const int K1 = in_sizes[0] / N;  // 128
    const int Mpad = (N + 63) & ~63; // 100032
    const int NB = (N + 255) >> 8;   // 391
    const int ntiles = Mpad / 64;    // 1563
    const int EB = (E + P1_CHUNK - 1) / P1_CHUNK;  // 391
    const int* src = ei;
    const int* dst = ei + E;

    char* p = (char*)d_ws;
    auto alloc = [&](size_t bytes) -> char* {
        char* r = p;
        p += (bytes + 255) & ~(size_t)255;
        return r;
    };
    // zero-init region (one memset): bktCnt | cnt | gsum, contiguous
    int*   bktCnt   = (int*)alloc((size_t)NB * 4);
    int*   cnt      = (int*)alloc(256 * 4);
    float* gsum     = (float*)alloc((size_t)G * 256 * 4);
    size_t zeroBytes = (size_t)((char*)(gsum + (size_t)G * 256) - (char*)bktCnt);
    int*   off      = (int*)alloc((size_t)(N + 1) * 4);
    float* dinv     = (float*)alloc((size_t)N * 4);
    float* scaleRaw = (float*)alloc((size_t)N * 4);
    float* scale0   = (float*)alloc((size_t)N * 4);
    float* scale1   = (float*)alloc((size_t)N * 4);
    int*   csr      = (int*)alloc((size_t)E * 4);
    unsigned* pairs = (unsigned*)alloc((size_t)NB * BCAP * 4);
    unsigned short* WT1 = (unsigned short*)alloc((size_t)256 * K1 * 2);
    unsigned short* WT2 = (unsigned short*)alloc((size_t)256 * 256 * 2);
    unsigned char*  Y0q4 = (unsigned char*)alloc((size_t)N * 64);   // uint4 [N][128]
    char*           Y1q4 = alloc((size_t)Mpad * 128);               // uint4 [Mpad][256]
    unsigned short* a1   = (unsigned short*)alloc((size_t)Mpad * K1 * 2);   // bf16
    unsigned short* a2   = (unsigned short*)alloc((size_t)Mpad * 256 * 2);  // bf16

    hipMemsetAsync(bktCnt, 0, zeroBytes, stream);

    int blkN = (N + 255) / 256;   // graph-hist blocks
    int PB = (N + 3) / 4;         // prescale blocks
    // merged: bucket scatter + W transposes + graph hist + x->uint4 prescale
    scatter_prep_kernel<<<EB + K1 + 256 + blkN + PB, 256, 0, stream>>>(
        src, dst, bktCnt, pairs, E, NB, EB, W1, WT1, K1, W2, WT2,
        batch, cnt, N, blkN, x, Y0q4, scaleRaw);
    fine_place_kernel<<<NB, 256, 0, stream>>>(
        pairs, bktCnt, off, dinv, scaleRaw, scale0, csr, N, E);

    // layer 1: uint4 gather -> bf16 a1 -> GEMM(W1) -> uint4 Y1q4 + scale1
    aggregate_q4x_kernel<<<(N + 3) / 4, 256, 0, stream>>>(
        Y0q4, scale0, a1, off, csr, dinv, N);
    mfma_gemm_kernel<128, 0><<<ntiles, 256, 0, stream>>>(
        a1, WT1, b1, dinv, Y1q4, scale1, nullptr, nullptr, N);
    // layer 2: uint4 gather -> bf16 a2 -> GEMM(W2) -> fused mean-pool
    aggregate_q4_kernel<<<(N + 3) / 4, 256, 0, stream>>>(
        (const unsigned short*)Y1q4, scale1, a2, off, csr, dinv, N);
    mfma_gemm_kernel<256, 1><<<ntiles, 256, 0, stream>>>(
        a2, WT2, b2, nullptr, nullptr, nullptr, batch, gsum, N);
    // head
    pool_final_kernel<<<G, 256, 0, stream>>>(gsum, cnt, Wc, bc, out);
}